// Round 1
// baseline (4083.380 us; speedup 1.0000x reference)
//
#include <hip/hip_runtime.h>
#include <math.h>

#define DD 257      // state dim
#define MM 128      // num rotation pairs
#define LL 512      // sequence length
#define BB 4        // batch
#define AP (DD+1)   // augmented row length (matrix | rhs)

// workspace layout (float offsets)
#define OFF_A  0        // 257*258 = 66306 floats: augmented [S | z0]
#define OFF_W0 66320    // 257 floats: w0 = S^-1 z0
#define OFF_TH 66592    // B*L*M = 262144 floats: cumulative angles
// total ~1.26 MB of ws

// Block 0: single-block Gaussian elimination with partial pivoting, S w0 = z0.
// Blocks 1..4: per-batch angle cumsum theta[b,l,m] = sum_{tau<=l} x[b,tau].om[m]
__global__ __launch_bounds__(256) void prep_kernel(const float* __restrict__ x,
                                                   const float* __restrict__ z0,
                                                   const float* __restrict__ om,
                                                   const float* __restrict__ S,
                                                   float* __restrict__ ws) {
  const int tid = threadIdx.x;
  if (blockIdx.x == 0) {
    float* A  = ws + OFF_A;
    float* w0 = ws + OFF_W0;
    __shared__ float piv_row[AP];
    __shared__ float mult[DD];
    __shared__ float red_val[256];
    __shared__ int   red_idx[256];
    __shared__ float xs[DD];

    // stage augmented matrix [S | z0]
    for (int idx = tid; idx < DD * DD; idx += 256) {
      int i = idx / DD;
      int j = idx - i * DD;
      A[i * AP + j] = S[idx];
    }
    for (int i = tid; i < DD; i += 256) A[i * AP + DD] = z0[i];
    __syncthreads();

    // forward elimination
    for (int k = 0; k < DD; ++k) {
      // partial pivot: argmax |A[i,k]|, i in [k, DD)
      float best = -1.0f; int bi = k;
      for (int i = k + tid; i < DD; i += 256) {
        float v = fabsf(A[i * AP + k]);
        if (v > best) { best = v; bi = i; }
      }
      red_val[tid] = best; red_idx[tid] = bi;
      __syncthreads();
      for (int s = 128; s > 0; s >>= 1) {
        if (tid < s && red_val[tid + s] > red_val[tid]) {
          red_val[tid] = red_val[tid + s]; red_idx[tid] = red_idx[tid + s];
        }
        __syncthreads();
      }
      const int p = red_idx[0];

      // swap rows k<->p, stage pivot row into LDS
      for (int j = k + tid; j <= DD; j += 256) {
        float ak = A[k * AP + j];
        if (p != k) {
          float ap_ = A[p * AP + j];
          A[k * AP + j] = ap_;
          A[p * AP + j] = ak;
          piv_row[j] = ap_;
        } else {
          piv_row[j] = ak;
        }
      }
      __syncthreads();

      const float pivinv = 1.0f / piv_row[k];
      for (int i = k + 1 + tid; i < DD; i += 256)
        mult[i] = A[i * AP + k] * pivinv;
      __syncthreads();

      // trailing update: 4 rows x 64 cols thread mapping (coalesced in j)
      const int ty = tid >> 6, tx = tid & 63;
      for (int i = k + 1 + ty; i < DD; i += 4) {
        const float m = mult[i];
        float* Ai = A + i * AP;
        for (int j = k + 1 + tx; j <= DD; j += 64) {
          Ai[j] -= m * piv_row[j];
        }
      }
      __syncthreads();
    }

    // back substitution
    for (int k = DD - 1; k >= 0; --k) {
      if (tid == 0) xs[k] = A[k * AP + DD] / A[k * AP + k];
      __syncthreads();
      const float xk = xs[k];
      for (int i = tid; i < k; i += 256)
        A[i * AP + DD] -= A[i * AP + k] * xk;
      __syncthreads();
    }
    for (int i = tid; i < DD; i += 256) w0[i] = xs[i];
  } else {
    // angle cumsum for batch b
    const int b = blockIdx.x - 1;
    __shared__ float xsh[LL * 2];
    for (int idx = tid; idx < LL * 2; idx += 256) xsh[idx] = x[b * LL * 2 + idx];
    __syncthreads();
    if (tid < MM) {
      const int m = tid;
      const float om0 = om[2 * m], om1 = om[2 * m + 1];
      float acc = 0.0f;
      float* th = ws + OFF_TH + (size_t)b * LL * MM + m;
      for (int l = 0; l < LL; ++l) {
        acc += xsh[2 * l] * om0 + xsh[2 * l + 1] * om1;
        th[(size_t)l * MM] = acc;   // coalesced across m
      }
    }
  }
}

// out[(b,l), i] = sum_d S[i,d] * W[(b,l), d]
// W[.,0] = w0[0]; W[.,2m+1] = c*w0[2m+1] - s*w0[2m+2]; W[.,2m+2] = s*w0[2m+1] + c*w0[2m+2]
#define NL 4
__global__ __launch_bounds__(320) void combine_kernel(const float* __restrict__ S,
                                                      const float* __restrict__ ws,
                                                      float* __restrict__ out) {
  const int tid = threadIdx.x;
  const int b  = blockIdx.y;
  const int l0 = blockIdx.x * NL;
  const float* w0 = ws + OFF_W0;
  const float* th = ws + OFF_TH;
  __shared__ float Wl[NL][DD];

  for (int idx = tid; idx < NL * DD; idx += 320) {
    const int r = idx / DD;
    const int d = idx - r * DD;
    const int l = l0 + r;
    float v;
    if (d == 0) {
      v = w0[0];
    } else {
      const int m = (d - 1) >> 1;       // works for both odd (2m+1) and even (2m+2)
      const int p = 2 * m + 1;
      const float t = th[(size_t)(b * LL + l) * MM + m];
      float s, c;
      sincosf(t, &s, &c);
      const float a0 = w0[p], a1 = w0[p + 1];
      v = (d & 1) ? (c * a0 - s * a1) : (s * a0 + c * a1);
    }
    Wl[r][d] = v;
  }
  __syncthreads();

  const int i = tid;
  if (i < DD) {
    const float* Si = S + (size_t)i * DD;
    float acc0 = 0.f, acc1 = 0.f, acc2 = 0.f, acc3 = 0.f;
    #pragma unroll 4
    for (int d = 0; d < DD; ++d) {
      const float sv = Si[d];
      acc0 += sv * Wl[0][d];
      acc1 += sv * Wl[1][d];
      acc2 += sv * Wl[2][d];
      acc3 += sv * Wl[3][d];
    }
    const size_t base = (size_t)(b * LL + l0) * DD + i;
    out[base]          = acc0;
    out[base + DD]     = acc1;
    out[base + 2 * DD] = acc2;
    out[base + 3 * DD] = acc3;
    if (l0 + NL == LL) {
      // z_final = outputs[:, L-1, :]
      out[(size_t)BB * LL * DD + (size_t)b * DD + i] = acc3;
    }
  }
}

extern "C" void kernel_launch(void* const* d_in, const int* in_sizes, int n_in,
                              void* d_out, int out_size, void* d_ws, size_t ws_size,
                              hipStream_t stream) {
  const float* x  = (const float*)d_in[0];   // (B, L, 2)
  const float* z0 = (const float*)d_in[1];   // (D,)
  const float* om = (const float*)d_in[2];   // (M, 2)
  const float* S  = (const float*)d_in[3];   // (D, D)
  float* ws  = (float*)d_ws;
  float* out = (float*)d_out;                // outputs (B,L,D) then z_final (B,D)

  hipLaunchKernelGGL(prep_kernel, dim3(1 + BB), dim3(256), 0, stream, x, z0, om, S, ws);
  hipLaunchKernelGGL(combine_kernel, dim3(LL / NL, BB), dim3(320), 0, stream, S, ws, out);
}